// Round 3
// baseline (995.674 us; speedup 1.0000x reference)
//
#include <hip/hip_runtime.h>

// LSTM B=512, T=512, H=256. Round 19 = byte-exact re-baseline of r16 (the
// previously harness-verified 997.5 us kernel). Rounds 0-2 returned zero
// signal (infra-style errors); r17/r18's XCD-L2 fast path is a suspect for a
// graph-replay-iteration>=2 deadlock (stale dirty handshake lines in a
// per-XCD L2 if replay node boundaries don't writeback/invalidate L2 the way
// normal launch boundaries provably do). This round disambiguates: r16 has no
// L2-resident handshake state (all record traffic is agent-scope sc1 -> LLC),
// so if THIS fails the same way, infra is conclusively broken; if it passes,
// we have baseline counters and r17/r18's protocol was the hang.
// ---- r16 description (unchanged): ----
// r15 wall: serial LLC handshake ~2500 cyc (publish -> vmcnt drain -> flag
// store RT -> flag poll RT -> tile read RT). Fix: each published h-pair is ONE
// atomic u64 {hi32 = seq = t+1, lo32 = 2 x fp16}. Consumer spins on its own
// records until seq == t -> drain, flag store, flag poll, and the separate
// data-read RT all deleted; the poll IS the data read.
// Safety (r10 induction, now self-tagged): parity slot written at steps t-1
// (seq t) and t+1 (seq t+2); partner's t+1 publish is gated on OUR step-t
// publish, which is barrier-ordered after OUR copier reads of its seq-t
// records -> no overwrite-before-read, and a spinner for seq==t cannot be
// skipped past. Monotone seq == exact match test.
// 256 blocks x 512 thr; grp=bid>>2 owns 8 batches; sub owns 64 h-cols;
// reg tier 32 VGPR (r14/r15-proven) + 64 KB wlds. Protocol otherwise r15.
// MFMA f32_16x16x32_f16: A=h[m=l16][k=quad*8+j], B=W[k][n=l16], D[m=quad*4+r][n].
// Weights prescaled by -log2e (i,f,o) / +2log2e (g).

typedef _Float16 half8 __attribute__((ext_vector_type(8)));
typedef float f32x4 __attribute__((ext_vector_type(4)));
typedef float f32x2 __attribute__((ext_vector_type(2)));

constexpr int kT = 512;
constexpr int kHF = 264;   // h_full row stride (halves)
constexpr float kLog2e = 1.44269504088896340736f;

#define ATL(p)    __hip_atomic_load((p), __ATOMIC_RELAXED, __HIP_MEMORY_SCOPE_AGENT)
#define ATS(p, v) __hip_atomic_store((p), (v), __ATOMIC_RELAXED, __HIP_MEMORY_SCOPE_AGENT)

// ws layout (bytes):
//   [0, 524288)          weight fragments fp16: frag (sub,c,g,kt) at half8 idx
//                        (sub*128 + (c*4+g)*8 + kt)*64 + lane
//   [524288, 1572864)    gbuf: tile(bid,par) = 256 u64 records at
//                        +(bid*2+par)*2048; record ri = hl*4 + pair,
//                        pair = quad*2+kh, m = quad*4 + kh*2 + rr
//   [1572864, 1581056)   pbuf float[256][8]
__global__ void prep_weights(const float* __restrict__ W_hh, _Float16* __restrict__ ws)
{
    int gid = blockIdx.x * blockDim.x + threadIdx.x;  // 0..32767, one half8 each
    int lane = gid & 63;
    int f = (gid >> 6) & 127;
    int sub = gid >> 13;
    int kt = f & 7, g = (f >> 3) & 3, c = f >> 5;
    int R = g * 256 + sub * 64 + c * 16 + (lane & 15);
    int k = kt * 32 + (lane >> 4) * 8;
    float s = (g == 2) ? 2.0f * kLog2e : -kLog2e;
    const float* src = W_hh + R * 256 + k;
    half8 v;
    #pragma unroll
    for (int j = 0; j < 8; ++j) v[j] = (_Float16)(src[j] * s);
    reinterpret_cast<half8*>(ws)[gid] = v;
}

__device__ __forceinline__ f32x4 mfma16(half8 a, half8 b, f32x4 c) {
    return __builtin_amdgcn_mfma_f32_16x16x32_f16(a, b, c, 0, 0, 0);
}

__global__ __launch_bounds__(512, 2)
void lstm_main(const float* __restrict__ ts,
               const float* __restrict__ W_ih,
               const float* __restrict__ b_ih,
               const float* __restrict__ b_hh,
               const float* __restrict__ W_out,
               const _Float16* __restrict__ wfrag,
               unsigned long long* __restrict__ gb64,
               float* __restrict__ pbuf)
{
    __shared__ __align__(16) _Float16 wlds[32768];        // 64 KB: jj=2,3 frags
    __shared__ __align__(16) _Float16 h_full[16][kHF];    // 8448 B (rows 8..15 stay 0)
    __shared__ __align__(16) float pacc1[4][2][4][16][10];// 20480 B
    __shared__ float red[4][8];

    const int tid  = threadIdx.x;
    const int w    = tid >> 6;
    const int lane = tid & 63;
    const int l16  = lane & 15;
    const int quad = lane >> 4;
    const int bid  = blockIdx.x;
    const int sub  = bid & 3;
    const int grp  = bid >> 2;     // 0..63
    const int b0   = grp * 8;
    const int c    = w & 3;        // column-group 0..3
    const int kh   = w >> 2;       // K-half 0..1

    const half8* wf8 = reinterpret_cast<const half8*>(wfrag) + sub * 8192;
    half8* wl8 = reinterpret_cast<half8*>(wlds);

    // stage LDS weight tier: frags (c,g,kh,jj) = src kt kh*4+2+jj
    for (int i = tid; i < 4096; i += 512) {
        int f = i >> 6, ln = i & 63;
        int jj = f & 1, kh_ = (f >> 1) & 1, g_ = (f >> 2) & 3, c_ = f >> 4;
        wl8[i] = wf8[(((c_ * 4 + g_) * 8) + kh_ * 4 + 2 + jj) * 64 + ln];
    }
    for (int i = tid; i < 16 * kHF; i += 512) (&h_full[0][0])[i] = (_Float16)0.0f;

    // ---- register weight tier: frags jj=0,1 (kt = kh*4 + jj), 32 VGPRs ----
    unsigned int wr_[8][4];
    #pragma unroll
    for (int g = 0; g < 4; ++g)
        #pragma unroll
        for (int jj = 0; jj < 2; ++jj) {
            uint4 v = *reinterpret_cast<const uint4*>(
                &wf8[(((c * 4 + g) * 8) + kh * 4 + jj) * 64 + lane]);
            int i = g * 2 + jj;
            wr_[i][0] = v.x; wr_[i][1] = v.y; wr_[i][2] = v.z; wr_[i][3] = v.w;
            asm volatile("" : "+v"(wr_[i][0]), "+v"(wr_[i][1]), "+v"(wr_[i][2]), "+v"(wr_[i][3]));
        }

    // per-col scalars
    float wih[4], bias[4];
    #pragma unroll
    for (int g = 0; g < 4; ++g) {
        int R = g * 256 + sub * 64 + c * 16 + l16;
        float s = (g == 2) ? 2.0f * kLog2e : -kLog2e;
        wih[g]  = W_ih[R] * s;
        bias[g] = (b_ih[R] + b_hh[R]) * s;
    }

    // copier mapping: tid>=128 handles 2 consecutive records of partner tile psub
    const int cs    = tid >> 7;            // 0 none; 1..3 partner offset
    const int psub  = (sub + cs) & 3;
    const int pbid  = (grp << 2) | psub;
    const int i0    = tid & 127;           // record-pair index
    const int chl   = i0 >> 1;             // hl 0..63
    const int cm0   = (i0 & 1) * 4;        // m base 0 or 4
    unsigned long long* myt[2] = { gb64 + (bid * 2 + 0) * 256, gb64 + (bid * 2 + 1) * 256 };

    float cst[2]  = {0.f, 0.f};
    float oacc[2] = {0.f, 0.f};

    __syncthreads();

    for (int t = 0; t < kT; ++t) {
        const int wpar = t & 1, rp = (t + 1) & 1;

        // in-loop re-pin (r14/r15-proven at this budget)
        #pragma unroll
        for (int i = 0; i < 8; ++i)
            asm volatile("" : "+v"(wr_[i][0]), "+v"(wr_[i][1]), "+v"(wr_[i][2]), "+v"(wr_[i][3]));

        // nonlin VMEM prefetch (quads 0,1 only)
        float tsv[2] = {0.f, 0.f};
        float wo = 0.f;
        if (quad < 2) {
            #pragma unroll
            for (int rr = 0; rr < 2; ++rr)
                tsv[rr] = ts[(b0 + quad * 4 + kh * 2 + rr) * kT + t];
            wo = W_out[t * 256 + sub * 64 + c * 16 + l16];
        }

        // copier: spin directly on its 2 self-tagged records (seq == t)
        if (cs >= 1) {
            const unsigned long long* pt = gb64 + (pbid * 2 + rp) * 256 + i0 * 2;
            unsigned long long v0, v1;
            const unsigned long long want = (unsigned long long)t;
            for (;;) {
                v0 = ATL(pt);
                v1 = ATL(pt + 1);
                if ((v0 >> 32) == want && (v1 >> 32) == want) break;
                __builtin_amdgcn_s_sleep(1);
            }
            union { unsigned int u; unsigned short s[2]; } a0, a1;
            a0.u = (unsigned int)v0; a1.u = (unsigned int)v1;
            reinterpret_cast<unsigned short*>(&h_full[cm0 + 0][psub * 64 + chl])[0] = a0.s[0];
            reinterpret_cast<unsigned short*>(&h_full[cm0 + 1][psub * 64 + chl])[0] = a0.s[1];
            reinterpret_cast<unsigned short*>(&h_full[cm0 + 2][psub * 64 + chl])[0] = a1.s[0];
            reinterpret_cast<unsigned short*>(&h_full[cm0 + 3][psub * 64 + chl])[0] = a1.s[1];
        }
        __syncthreads();   // b_copy: h_full rows 0..7 = full h_{t-1}

        // A fragments + MFMA (jj=0,1 regs; jj=2,3 LDS)
        half8 a[4];
        #pragma unroll
        for (int j = 0; j < 4; ++j)
            a[j] = *reinterpret_cast<const half8*>(&h_full[l16][(kh * 4 + j) * 32 + quad * 8]);
        f32x4 gacc[4];
        #pragma unroll
        for (int g = 0; g < 4; ++g) { f32x4 z = {0.f, 0.f, 0.f, 0.f}; gacc[g] = z; }
        #pragma unroll
        for (int jj = 0; jj < 2; ++jj)
            #pragma unroll
            for (int g = 0; g < 4; ++g) {
                int i = g * 2 + jj;
                half8 wv = __builtin_bit_cast(half8,
                    make_uint4(wr_[i][0], wr_[i][1], wr_[i][2], wr_[i][3]));
                gacc[g] = mfma16(a[jj], wv, gacc[g]);
            }
        #pragma unroll
        for (int jj = 0; jj < 2; ++jj)
            #pragma unroll
            for (int g = 0; g < 4; ++g)
                gacc[g] = mfma16(a[2 + jj],
                                 wl8[(((c * 4 + g) * 4) + kh * 2 + jj) * 64 + lane], gacc[g]);

        // pacc: exchange my OTHER two rows with the partner kh wave
        #pragma unroll
        for (int g = 0; g < 4; ++g) {
            f32x2 v; v.x = gacc[g][(1 - kh) * 2 + 0]; v.y = gacc[g][(1 - kh) * 2 + 1];
            *reinterpret_cast<f32x2*>(&pacc1[c][kh][g][l16][quad * 2]) = v;
        }
        __syncthreads();   // b1: pacc exchanged; all A-reads drained

        // nonlin (quads 0,1): rows m = quad*4 + kh*2 + rr
        if (quad < 2) {
            f32x2 p[4];
            #pragma unroll
            for (int g = 0; g < 4; ++g)
                p[g] = *reinterpret_cast<const f32x2*>(&pacc1[c][1 - kh][g][l16][quad * 2]);
            const int hl = c * 16 + l16;
            const int hk = sub * 64 + hl;
            union { unsigned int u; unsigned short s[2]; } hp;
            #pragma unroll
            for (int rr = 0; rr < 2; ++rr) {
                int ro = kh * 2 + rr;
                float pg[4] = { rr ? p[0].y : p[0].x, rr ? p[1].y : p[1].x,
                                rr ? p[2].y : p[2].x, rr ? p[3].y : p[3].x };
                float gi = gacc[0][ro] + pg[0] + (tsv[rr] * wih[0] + bias[0]);
                float gf = gacc[1][ro] + pg[1] + (tsv[rr] * wih[1] + bias[1]);
                float gg = gacc[2][ro] + pg[2] + (tsv[rr] * wih[2] + bias[2]);
                float go = gacc[3][ro] + pg[3] + (tsv[rr] * wih[3] + bias[3]);
                float I = __builtin_amdgcn_rcpf(1.0f + __builtin_amdgcn_exp2f(gi));
                float F = __builtin_amdgcn_rcpf(1.0f + __builtin_amdgcn_exp2f(gf));
                float G = 1.0f - 2.0f * __builtin_amdgcn_rcpf(1.0f + __builtin_amdgcn_exp2f(gg));
                float O = __builtin_amdgcn_rcpf(1.0f + __builtin_amdgcn_exp2f(go));
                float cn = F * cst[rr] + I * G;
                cst[rr] = cn;
                float tc = 1.0f - 2.0f * __builtin_amdgcn_rcpf(
                               1.0f + __builtin_amdgcn_exp2f(2.0f * kLog2e * cn));
                float hv = O * tc;
                oacc[rr] += hv * wo;
                _Float16 h16 = (_Float16)hv;
                hp.s[rr] = __builtin_bit_cast(unsigned short, h16);
                h_full[quad * 4 + ro][hk] = h16;    // own-sub LDS copy for t+1
            }
            // fused publish: one u64 {seq = t+1, 2 x fp16} — no drain, no flag
            unsigned long long rec = ((unsigned long long)(t + 1) << 32) | hp.u;
            ATS(myt[wpar] + (hl * 4 + quad * 2 + kh), rec);
        }
        // no end barrier (r13..r15-proven)
    }

    // ---- output partials: reduce over l16 (cols); quads 0,1 fill red ----
    #pragma unroll
    for (int rr = 0; rr < 2; ++rr) {
        float v = oacc[rr];
        v += __shfl_xor(v, 1, 64);
        v += __shfl_xor(v, 2, 64);
        v += __shfl_xor(v, 4, 64);
        v += __shfl_xor(v, 8, 64);
        if (l16 == 0 && quad < 2) red[c][quad * 4 + kh * 2 + rr] = v;
    }
    __syncthreads();
    if (tid < 8) {
        float s = 0.f;
        #pragma unroll
        for (int cc = 0; cc < 4; ++cc) s += red[cc][tid];
        pbuf[bid * 8 + tid] = s;
    }
}

__global__ void finalize(const float* __restrict__ pbuf,
                         const float* __restrict__ b_out,
                         float* __restrict__ out)
{
    int b = blockIdx.x * blockDim.x + threadIdx.x;   // 0..511
    int grp = b >> 3, m = b & 7;
    float s = b_out[0];
    #pragma unroll
    for (int s4 = 0; s4 < 4; ++s4) s += pbuf[((grp * 4 + s4) * 8) + m];
    out[b] = s;
}

extern "C" void kernel_launch(void* const* d_in, const int* in_sizes, int n_in,
                              void* d_out, int out_size, void* d_ws, size_t ws_size,
                              hipStream_t stream) {
    const float* ts    = (const float*)d_in[0];
    const float* W_ih  = (const float*)d_in[1];
    const float* W_hh  = (const float*)d_in[2];
    const float* b_ih  = (const float*)d_in[3];
    const float* b_hh  = (const float*)d_in[4];
    const float* W_out = (const float*)d_in[5];
    const float* b_out = (const float*)d_in[6];

    char* wsb = (char*)d_ws;
    _Float16*           wfrag = (_Float16*)wsb;
    unsigned long long* gb64  = (unsigned long long*)(wsb + 524288);
    float*              pbuf  = (float*)(wsb + 1572864);

    // zero gbuf (t=0 spins expect seq 0 / zero data on parity-1) + pbuf
    hipMemsetAsync(wsb + 524288, 0, 1048576 + 8192, stream);
    prep_weights<<<128, 256, 0, stream>>>(W_hh, wfrag);
    lstm_main<<<256, 512, 0, stream>>>(ts, W_ih, b_ih, b_hh, W_out,
                                       wfrag, gb64, pbuf);
    finalize<<<1, 512, 0, stream>>>(pbuf, b_out, (float*)d_out);
}